// Round 5
// baseline (54.252 us; speedup 1.0000x reference)
//
#include <hip/hip_runtime.h>

// EMA / first-order low-pass scan: s_t = alpha[d] * s_{t-1} + x[b,d,t]
// x: [B, D, T] fp32 contiguous; alpha: [D] fp32.
// out: psp [B,D,T] followed by final_state [B,D] (flat, fp32).
//
// R1 structure (best: 46.6us): one 64-lane wave per sequence, lane owns 8
// contiguous elements; wave-parallel linear-recurrence scan via shfl_up.
// R5 experiment: NONTEMPORAL LOADS on the input stream. Rationale: in+out
// (269 MB) > L3 (256 MB); normal loads let the input fight the output for
// L3, leaving writes to stream to HBM every replay. nt-loads keep input out
// of L3 so the output can stay L3-resident as a write-back buffer.
// (nt-STORES regressed hard in R3: WRITE_SIZE 131.6->228.4 MB; loads only.)

#define BB 32
#define DD 2048
#define TT 512
#define NSEQ (BB * DD)   // 65536 sequences

typedef float f32x4 __attribute__((ext_vector_type(4)));

__global__ __launch_bounds__(256) void ema_scan_kernel(
    const float* __restrict__ x,
    const float* __restrict__ alpha_arr,
    float* __restrict__ psp,
    float* __restrict__ final_state)
{
    // one 64-lane wave per sequence
    const int gtid = blockIdx.x * 256 + threadIdx.x;
    const int seq  = gtid >> 6;          // wave id == sequence id
    const int lane = threadIdx.x & 63;
    if (seq >= NSEQ) return;

    const int d = seq & (DD - 1);        // D = 2048 (power of two)
    const float alpha = alpha_arr[d];

    const float* xp = x + (size_t)seq * TT + (size_t)lane * 8;

    f32x4 v0 = __builtin_nontemporal_load(reinterpret_cast<const f32x4*>(xp));
    f32x4 v1 = __builtin_nontemporal_load(reinterpret_cast<const f32x4*>(xp + 4));

    // Local inclusive scan over this lane's 8 elements, assuming incoming state 0.
    float y0 = v0.x;
    float y1 = fmaf(alpha, y0, v0.y);
    float y2 = fmaf(alpha, y1, v0.z);
    float y3 = fmaf(alpha, y2, v0.w);
    float y4 = fmaf(alpha, y3, v1.x);
    float y5 = fmaf(alpha, y4, v1.y);
    float y6 = fmaf(alpha, y5, v1.z);
    float y7 = fmaf(alpha, y6, v1.w);

    // This lane's segment transform: s_out = A * s_in + Bc, with A = alpha^8.
    const float a2 = alpha * alpha;
    const float a4 = a2 * a2;
    float A  = a4 * a4;                  // alpha^8
    float Bc = y7;

    // Wave-inclusive scan of transforms: combined = cur ∘ prev
    //   A' = A_prev * A_cur;  B' = A_cur * B_prev + B_cur
    #pragma unroll
    for (int off = 1; off < 64; off <<= 1) {
        float aP = __shfl_up(A,  off);
        float bP = __shfl_up(Bc, off);
        if (lane >= off) {
            Bc = fmaf(A, bP, Bc);
            A  = A * aP;
        }
    }

    // Exclusive: incoming state for this lane = previous lane's inclusive B.
    float s_in = __shfl_up(Bc, 1);
    if (lane == 0) s_in = 0.0f;

    // Fixup: y_j += alpha^(j+1) * s_in
    float pw = alpha;
    y0 = fmaf(pw, s_in, y0); pw *= alpha;
    y1 = fmaf(pw, s_in, y1); pw *= alpha;
    y2 = fmaf(pw, s_in, y2); pw *= alpha;
    y3 = fmaf(pw, s_in, y3); pw *= alpha;
    y4 = fmaf(pw, s_in, y4); pw *= alpha;
    y5 = fmaf(pw, s_in, y5); pw *= alpha;
    y6 = fmaf(pw, s_in, y6); pw *= alpha;
    y7 = fmaf(pw, s_in, y7);

    float* op = psp + (size_t)seq * TT + (size_t)lane * 8;
    f32x4 o0 = {y0, y1, y2, y3};
    f32x4 o1 = {y4, y5, y6, y7};
    *reinterpret_cast<f32x4*>(op)     = o0;
    *reinterpret_cast<f32x4*>(op + 4) = o1;

    if (lane == 63) {
        final_state[seq] = y7;           // full-sequence final state
    }
}

extern "C" void kernel_launch(void* const* d_in, const int* in_sizes, int n_in,
                              void* d_out, int out_size, void* d_ws, size_t ws_size,
                              hipStream_t stream) {
    const float* x     = (const float*)d_in[0];   // [B, D, T]
    const float* alpha = (const float*)d_in[1];   // [D]
    float* psp         = (float*)d_out;                      // [B, D, T]
    float* final_state = (float*)d_out + (size_t)NSEQ * TT;  // [B, D]

    // 65536 sequences, 1 wave (64 lanes) each -> 4 waves per 256-thread block
    const int blocks = NSEQ / 4;   // 16384
    ema_scan_kernel<<<blocks, 256, 0, stream>>>(x, alpha, psp, final_state);
}

// Round 6
// 45.971 us; speedup vs baseline: 1.1801x; 1.1801x over previous
//
#include <hip/hip_runtime.h>

// EMA / first-order low-pass scan: s_t = alpha[d] * s_{t-1} + x[b,d,t]
// x: [B, D, T] fp32 contiguous; alpha: [D] fp32.
// out: psp [B,D,T] followed by final_state [B,D] (flat, fp32).
//
// FINAL (R1 structure, best measured 46.6us = 92% of 6.29 TB/s copy ceiling):
// one 64-lane wave per sequence; lane i owns elements [8i, 8i+8); coalesced
// float4 loads/stores; sequential dependence resolved by a wave-parallel
// linear-recurrence scan: local 8-FMA chain -> 6-step shfl_up composition
// scan of (A,B) transforms -> 8-FMA fixup with the incoming state.
// Measured dead ends: SPW=4 MLP (48.2us, not latency-bound), nt-stores
// (84.4us, WRITE_SIZE 131.6->228.4 MB), nt-loads (54.3us).

#define BB 32
#define DD 2048
#define TT 512
#define NSEQ (BB * DD)   // 65536 sequences

typedef float f32x4 __attribute__((ext_vector_type(4)));

__global__ __launch_bounds__(256) void ema_scan_kernel(
    const float* __restrict__ x,
    const float* __restrict__ alpha_arr,
    float* __restrict__ psp,
    float* __restrict__ final_state)
{
    // one 64-lane wave per sequence
    const int gtid = blockIdx.x * 256 + threadIdx.x;
    const int seq  = gtid >> 6;          // wave id == sequence id
    const int lane = threadIdx.x & 63;
    if (seq >= NSEQ) return;

    const int d = seq & (DD - 1);        // D = 2048 (power of two)
    const float alpha = alpha_arr[d];

    const float* xp = x + (size_t)seq * TT + (size_t)lane * 8;

    f32x4 v0 = *reinterpret_cast<const f32x4*>(xp);
    f32x4 v1 = *reinterpret_cast<const f32x4*>(xp + 4);

    // Local inclusive scan over this lane's 8 elements, assuming incoming state 0.
    float y0 = v0.x;
    float y1 = fmaf(alpha, y0, v0.y);
    float y2 = fmaf(alpha, y1, v0.z);
    float y3 = fmaf(alpha, y2, v0.w);
    float y4 = fmaf(alpha, y3, v1.x);
    float y5 = fmaf(alpha, y4, v1.y);
    float y6 = fmaf(alpha, y5, v1.z);
    float y7 = fmaf(alpha, y6, v1.w);

    // This lane's segment transform: s_out = A * s_in + Bc, with A = alpha^8.
    const float a2 = alpha * alpha;
    const float a4 = a2 * a2;
    float A  = a4 * a4;                  // alpha^8
    float Bc = y7;

    // Wave-inclusive scan of transforms: combined = cur ∘ prev
    //   A' = A_prev * A_cur;  B' = A_cur * B_prev + B_cur
    #pragma unroll
    for (int off = 1; off < 64; off <<= 1) {
        float aP = __shfl_up(A,  off);
        float bP = __shfl_up(Bc, off);
        if (lane >= off) {
            Bc = fmaf(A, bP, Bc);
            A  = A * aP;
        }
    }

    // Exclusive: incoming state for this lane = previous lane's inclusive B.
    float s_in = __shfl_up(Bc, 1);
    if (lane == 0) s_in = 0.0f;

    // Fixup: y_j += alpha^(j+1) * s_in
    float pw = alpha;
    y0 = fmaf(pw, s_in, y0); pw *= alpha;
    y1 = fmaf(pw, s_in, y1); pw *= alpha;
    y2 = fmaf(pw, s_in, y2); pw *= alpha;
    y3 = fmaf(pw, s_in, y3); pw *= alpha;
    y4 = fmaf(pw, s_in, y4); pw *= alpha;
    y5 = fmaf(pw, s_in, y5); pw *= alpha;
    y6 = fmaf(pw, s_in, y6); pw *= alpha;
    y7 = fmaf(pw, s_in, y7);

    float* op = psp + (size_t)seq * TT + (size_t)lane * 8;
    f32x4 o0 = {y0, y1, y2, y3};
    f32x4 o1 = {y4, y5, y6, y7};
    *reinterpret_cast<f32x4*>(op)     = o0;
    *reinterpret_cast<f32x4*>(op + 4) = o1;

    if (lane == 63) {
        final_state[seq] = y7;           // full-sequence final state
    }
}

extern "C" void kernel_launch(void* const* d_in, const int* in_sizes, int n_in,
                              void* d_out, int out_size, void* d_ws, size_t ws_size,
                              hipStream_t stream) {
    const float* x     = (const float*)d_in[0];   // [B, D, T]
    const float* alpha = (const float*)d_in[1];   // [D]
    float* psp         = (float*)d_out;                      // [B, D, T]
    float* final_state = (float*)d_out + (size_t)NSEQ * TT;  // [B, D]

    // 65536 sequences, 1 wave (64 lanes) each -> 4 waves per 256-thread block
    const int blocks = NSEQ / 4;   // 16384
    ema_scan_kernel<<<blocks, 256, 0, stream>>>(x, alpha, psp, final_state);
}